// Round 1
// baseline (241.845 us; speedup 1.0000x reference)
//
#include <hip/hip_runtime.h>
#include <hip/hip_bf16.h>
#include <stdint.h>

#define J_N   24
#define CIN   96
#define COUT  192
#define KS    15
#define PADV  7
#define BATCH 128
#define TLEN  4096
#define NPAIR 12
#define TT    256

typedef short short8 __attribute__((ext_vector_type(8)));
typedef float f32x4 __attribute__((ext_vector_type(4)));

__device__ __forceinline__ unsigned short f2bf(float f) {
    unsigned int u = __float_as_uint(f);
    u = u + 0x7fffu + ((u >> 16) & 1u);
    return (unsigned short)(u >> 16);
}

// Build masked bf16 weight fragments: wf[p][co_l][kk], kk = k*16 + ci_l.
// ci slot l -> joint jn = 2p-1 + l/4 (4-joint neighbor union), zero if invalid
// or outside the skeleton mask or k==15 (K padding 15->16).
__global__ __launch_bounds__(256) void prep_weights_kernel(
    const float* __restrict__ w, unsigned short* __restrict__ wf)
{
    int e = blockIdx.x * 256 + threadIdx.x;   // 12*16*256 = 49152 entries
    int kk   = e & 255;
    int co_l = (e >> 8) & 15;
    int p    = e >> 12;
    int k    = kk >> 4;
    int ci_l = kk & 15;
    int jo = 2 * p + (co_l >> 3);
    int jn = 2 * p - 1 + (ci_l >> 2);
    int ci_g = 8 * p - 4 + ci_l;
    float v = 0.0f;
    if (k < KS && jn >= 0 && jn < J_N && jn >= jo - 1 && jn <= jo + 1) {
        v = w[((size_t)(16 * p + co_l) * CIN + ci_g) * KS + k];
    }
    wf[e] = f2bf(v);
}

__global__ __launch_bounds__(256) void skel_conv_kernel(
    const float* __restrict__ x, const unsigned short* __restrict__ wf,
    const float* __restrict__ bias, float* __restrict__ out)
{
    // x tile: [tl][ci_l] bf16, row stride 24 ushorts (48 B) for bank spread
    __shared__ unsigned short xlds[272 * 24];

    const int tid = threadIdx.x;
    const int t0  = blockIdx.x * TT;
    const int b   = blockIdx.y;
    const int p   = blockIdx.z;

    // ---- stage x tile (272 t-rows incl. halo, reflect handled here) ----
    {
        const float* xb = x + (size_t)b * CIN * TLEN;
        for (int H = tid; H < 544; H += 256) {   // 272 rows * 2 halves
            int tl = H >> 1;
            int h  = H & 1;
            int tg = t0 - PADV + tl;
            int src = tg < 0 ? -tg : (tg >= TLEN ? 2 * TLEN - 2 - tg : tg);
            int cigbase = 8 * p - 4 + 8 * h;
            short8 v8;
            #pragma unroll
            for (int j = 0; j < 8; ++j) {
                int cig = cigbase + j;
                float v = (cig >= 0 && cig < CIN) ? xb[(size_t)cig * TLEN + src] : 0.0f;
                v8[j] = (short)f2bf(v);
            }
            *reinterpret_cast<short8*>(&xlds[tl * 24 + 8 * h]) = v8;
        }
    }
    __syncthreads();

    const int lane = tid & 63;
    const int wave = tid >> 6;
    const int col  = lane & 15;       // A row (co) / B,D col (t)
    const int hi2  = lane >> 4;       // K sub-block selector

    // ---- A fragments: 8 K-slices of masked weights, kept in registers ----
    short8 afrag[8];
    {
        const unsigned short* wfp = wf + (size_t)(p * 16 + col) * 256 + hi2 * 8;
        #pragma unroll
        for (int s = 0; s < 8; ++s)
            afrag[s] = *reinterpret_cast<const short8*>(wfp + s * 32);
    }

    const int ci0b = (hi2 & 1) * 8;   // ci base for this lane's B elements
    const int kb   = hi2 >> 1;        // k-tap low bit

    f32x4 acc[4];
    #pragma unroll
    for (int nf = 0; nf < 4; ++nf) acc[nf] = (f32x4){0.f, 0.f, 0.f, 0.f};

    #pragma unroll
    for (int nf = 0; nf < 4; ++nf) {
        const int ntl = wave * 64 + nf * 16 + col;            // local out t
        const unsigned short* bp = &xlds[(ntl + kb) * 24 + ci0b];
        #pragma unroll
        for (int s = 0; s < 8; ++s) {
            // k-tap = 2s + kb  ->  row offset 2s  ->  +48 ushorts per s
            short8 bfrag = *reinterpret_cast<const short8*>(bp + s * 48);
            acc[nf] = __builtin_amdgcn_mfma_f32_16x16x32_bf16(afrag[s], bfrag, acc[nf], 0, 0, 0);
        }
    }

    // ---- epilogue: D row = co_l = 4*hi2 + r, col = t ----
    const int colb = 4 * hi2;
    float bv[4];
    #pragma unroll
    for (int r = 0; r < 4; ++r) bv[r] = bias[16 * p + colb + r];

    #pragma unroll
    for (int nf = 0; nf < 4; ++nf) {
        int t = t0 + wave * 64 + nf * 16 + col;
        #pragma unroll
        for (int r = 0; r < 4; ++r) {
            int co = 16 * p + colb + r;
            out[((size_t)b * COUT + co) * TLEN + t] = acc[nf][r] + bv[r];
        }
    }
}

extern "C" void kernel_launch(void* const* d_in, const int* in_sizes, int n_in,
                              void* d_out, int out_size, void* d_ws, size_t ws_size,
                              hipStream_t stream) {
    const float* x    = (const float*)d_in[0];
    const float* w    = (const float*)d_in[1];
    const float* bias = (const float*)d_in[2];
    float* out        = (float*)d_out;
    unsigned short* wf = (unsigned short*)d_ws;   // needs 98304 B

    prep_weights_kernel<<<dim3(192), dim3(256), 0, stream>>>(w, wf);
    skel_conv_kernel<<<dim3(TLEN / TT, BATCH, NPAIR), dim3(256), 0, stream>>>(
        x, wf, bias, out);
}